// Round 1
// baseline (9.324 us; speedup 1.0000x reference)
//
#include <hip/hip_runtime.h>

// Q=3, R=128, V=64, EPS=0.4999999
// Key insight: flat_idx = (i0*R^2 + i1*R + i2) % R == i2 % R, since R^2 and R
// are multiples of R. Only the first R rows (R*V floats = 32 KB) of storage
// are ever read. The whole op is 8 gathers of 64 floats + a weighted sum.

#define QQ 3
#define RR 128
#define VV 64
#define KB_EPS 0.4999999f

__global__ __launch_bounds__(64) void kb_kernel(
    const float* __restrict__ query,
    const float* __restrict__ storage,
    float* __restrict__ out)
{
    const int v = threadIdx.x;  // 0..63, one output element per lane

    // saw[j] = (q - floor(q)) * R   (wave-uniform scalar work, done per-lane)
    float saw[QQ];
#pragma unroll
    for (int j = 0; j < QQ; ++j) {
        const float q = query[j];
        saw[j] = (q - floorf(q)) * (float)RR;
    }

    float acc = 0.0f;
#pragma unroll
    for (int i = 0; i < (1 << QQ); ++i) {
        int flat = 0;
        float w = 0.0f;
#pragma unroll
        for (int j = 0; j < QQ; ++j) {
            // neighbor_map row i, element j: -EPS iff bit (Q-1-j) of i is set
            const float off = ((i >> (QQ - 1 - j)) & 1) ? -KB_EPS : KB_EPS;
            const float idxf = rintf(saw[j] + off);   // jnp.round = half-to-even
            const int   idx  = (int)idxf;             // already integral
            flat = flat * RR + idx;                   // Horner: i0*R^2+i1*R+i2
            w += 1.0f - fabsf(idxf - saw[j]);
        }
        // Python-style mod (operands are non-negative here, but be faithful)
        int fidx = flat % RR;
        if (fidx < 0) fidx += RR;
        acc += w * storage[(size_t)fidx * VV + v];
    }

    out[v] = acc * (1.0f / (float)QQ);
}

extern "C" void kernel_launch(void* const* d_in, const int* in_sizes, int n_in,
                              void* d_out, int out_size, void* d_ws, size_t ws_size,
                              hipStream_t stream) {
    const float* query   = (const float*)d_in[0];
    const float* storage = (const float*)d_in[1];
    float* out = (float*)d_out;
    kb_kernel<<<1, 64, 0, stream>>>(query, storage, out);
}